// Round 2
// baseline (187.190 us; speedup 1.0000x reference)
//
#include <hip/hip_runtime.h>
#include <math.h>

// Problem constants (from reference setup_inputs)
#define BB 8
#define CC 192
#define HH 128
#define WW 128
#define RPS 8         // rows per row-stream (8 streams x 8 = 64 rows per block)
#define BANDS 2       // 2 blocks per (b,c) image, 64-row bands
#define DPF 6         // prefetch depth (loads in flight per thread)
#define NB  (DPF + 1) // circular buffer slots

typedef float vf4 __attribute__((ext_vector_type(4)));

__device__ __forceinline__ float col9(float a0, float a1, float a2,
                                      float b0, float b1, float b2,
                                      float c0, float c1, float c2,
                                      float th, const float* kk) {
    float m;
    m = fmaf(th, kk[0], a0);
    m = fmaxf(m, fmaf(th, kk[1], a1));
    m = fmaxf(m, fmaf(th, kk[2], a2));
    m = fmaxf(m, fmaf(th, kk[3], b0));
    m = fmaxf(m, fmaf(th, kk[4], b1));
    m = fmaxf(m, fmaf(th, kk[5], b2));
    m = fmaxf(m, fmaf(th, kk[6], c0));
    m = fmaxf(m, fmaf(th, kk[7], c1));
    m = fmaxf(m, fmaf(th, kk[8], c2));
    return m;
}

__global__ __launch_bounds__(256) void dynmorph_kernel(
    const float* __restrict__ x,      // [B, C, H, W]
    const float* __restrict__ kern,   // [C, 9]
    const float* __restrict__ gw,     // [C]
    const float* __restrict__ gb,     // [C]
    float* __restrict__ out)          // [B, C, H, W]
{
    const int tid  = threadIdx.x;
    const int lane = tid & 63;
    const int wg   = lane & 31;                      // column group: cols 4*wg..4*wg+3
    const int rs   = (tid >> 6) * 2 + (lane >> 5);   // row-stream 0..7
    const int col  = wg * 4;

    // grid = BB*CC*BANDS: blockIdx.x = bc*BANDS + band
    const int bc   = blockIdx.x / BANDS;             // b*C + c  (block-uniform)
    const int band = blockIdx.x - bc * BANDS;        // 0 or 1: which 64-row band
    const int c    = bc % CC;
    const int r0   = band * (8 * RPS) + rs * RPS;    // first output row of this stream

    const float* xp = x   + (size_t)bc * (HH * WW);
    float*       op = out + (size_t)bc * (HH * WW);

    // Block-uniform coefficients -> SGPRs
    float kk[9];
#pragma unroll
    for (int i = 0; i < 9; ++i) kk[i] = kern[c * 9 + i];
    const float gwc = gw[c];
    const float gbc = gb[c];

    // load idx i  <->  global row (r0 - 1 + i), i in [0, RPS+2)
    auto ld = [&](int i) -> vf4 {
        const int g = r0 - 1 + i;
        if (g >= 0 && g < HH) return *(const vf4*)(xp + g * WW + col);
        return (vf4)(0.0f);
    };

    vf4   buf[NB];
    float lfh[RPS + 2], rth[RPS + 2];

    // ---- Prologue: fill the pipe with DPF loads ----
#pragma unroll
    for (int i = 0; i < DPF; ++i) buf[i % NB] = ld(i);
    __builtin_amdgcn_sched_barrier(0);

    // Halos for idx 0,1 (idx 2's halo comes in iteration 0)
#pragma unroll
    for (int i = 0; i < 2; ++i) {
        const vf4 t = buf[i % NB];
        const float l = __shfl_up(t.w, 1);
        const float r = __shfl_down(t.x, 1);
        lfh[i] = (wg == 0)  ? 0.0f : l;
        rth[i] = (wg == 31) ? 0.0f : r;
    }

    // ---- Steady-state: load(g+DPF) ahead of compute(g), every iteration ----
#pragma unroll
    for (int g = 0; g < RPS; ++g) {
        if (g + DPF < RPS + 2) {
            buf[(g + DPF) % NB] = ld(g + DPF);
        }
        __builtin_amdgcn_sched_barrier(0);   // prefetch may not sink below compute

        // Halo for the newest row this iteration consumes (idx g+2)
        {
            const vf4 t = buf[(g + 2) % NB];
            const float l = __shfl_up(t.w, 1);
            const float r = __shfl_down(t.x, 1);
            lfh[g + 2] = (wg == 0)  ? 0.0f : l;
            rth[g + 2] = (wg == 31) ? 0.0f : r;
        }

        const vf4 A  = buf[g % NB];
        const vf4 B  = buf[(g + 1) % NB];
        const vf4 Cv = buf[(g + 2) % NB];

        const float t0 = __builtin_amdgcn_rcpf(1.0f + __expf(-fmaf(B.x, gwc, gbc)));
        const float t1 = __builtin_amdgcn_rcpf(1.0f + __expf(-fmaf(B.y, gwc, gbc)));
        const float t2 = __builtin_amdgcn_rcpf(1.0f + __expf(-fmaf(B.z, gwc, gbc)));
        const float t3 = __builtin_amdgcn_rcpf(1.0f + __expf(-fmaf(B.w, gwc, gbc)));

        vf4 o;
        o.x = col9(lfh[g],   A.x, A.y,
                   lfh[g+1], B.x, B.y,
                   lfh[g+2], Cv.x, Cv.y, t0, kk);
        o.y = col9(A.x, A.y, A.z,
                   B.x, B.y, B.z,
                   Cv.x, Cv.y, Cv.z, t1, kk);
        o.z = col9(A.y, A.z, A.w,
                   B.y, B.z, B.w,
                   Cv.y, Cv.z, Cv.w, t2, kk);
        o.w = col9(A.z, A.w, rth[g],
                   B.z, B.w, rth[g+1],
                   Cv.z, Cv.w, rth[g+2], t3, kk);

        *(vf4*)(op + (r0 + g) * WW + col) = o;
    }
}

extern "C" void kernel_launch(void* const* d_in, const int* in_sizes, int n_in,
                              void* d_out, int out_size, void* d_ws, size_t ws_size,
                              hipStream_t stream) {
    const float* x    = (const float*)d_in[0];
    const float* kern = (const float*)d_in[1];
    const float* gw   = (const float*)d_in[2];
    const float* gb   = (const float*)d_in[3];
    float* out        = (float*)d_out;

    // 3072 blocks: 12 queued per CU, 8 resident (32 waves = 100% of slots),
    // 4 backfill as blocks finish. Was 1536 = 6/CU = 24/32 slots, no backfill.
    dim3 grid(BB * CC * BANDS);
    dim3 block(256);
    dynmorph_kernel<<<grid, block, 0, stream>>>(x, kern, gw, gb, out);
}

// Round 3
// 184.968 us; speedup vs baseline: 1.0120x; 1.0120x over previous
//
#include <hip/hip_runtime.h>
#include <math.h>

// Problem constants (from reference setup_inputs)
#define BB 8
#define CC 192
#define HH 128
#define WW 128

#define GR    8                 // rows per group (block loads/computes 8 rows per iter)
#define NG    16                // compute iterations: 128 rows / 8
#define ROWF  136               // floats per LDS row: 4 zero-pad + 128 + 4 zero-pad
#define SLOTF (GR * ROWF)       // 1088 floats per ring slot
#define LDSF  (4 * SLOTF)       // 4 slots = 4352 floats = 17408 B

typedef float vf4 __attribute__((ext_vector_type(4)));
typedef float vf2 __attribute__((ext_vector_type(2)));

__device__ __forceinline__ float col9(float a0, float a1, float a2,
                                      float b0, float b1, float b2,
                                      float c0, float c1, float c2,
                                      float th, const float* kk) {
    float m;
    m = fmaf(th, kk[0], a0);
    m = fmaxf(m, fmaf(th, kk[1], a1));
    m = fmaxf(m, fmaf(th, kk[2], a2));
    m = fmaxf(m, fmaf(th, kk[3], b0));
    m = fmaxf(m, fmaf(th, kk[4], b1));
    m = fmaxf(m, fmaf(th, kk[5], b2));
    m = fmaxf(m, fmaf(th, kk[6], c0));
    m = fmaxf(m, fmaf(th, kk[7], c1));
    m = fmaxf(m, fmaf(th, kk[8], c2));
    return m;
}

__global__ __launch_bounds__(256) void dynmorph_kernel(
    const float* __restrict__ x,      // [B, C, H, W]
    const float* __restrict__ kern,   // [C, 9]
    const float* __restrict__ gw,     // [C]
    const float* __restrict__ gb,     // [C]
    float* __restrict__ out)          // [B, C, H, W]
{
    __shared__ float smem[LDSF];

    const int tid  = threadIdx.x;
    const int lane = tid & 63;
    const int wg   = lane & 31;                      // column group: cols 4*wg..4*wg+3
    const int rs   = (tid >> 6) * 2 + (lane >> 5);   // row-in-group 0..7
    const int col  = wg * 4;

    const int bc = blockIdx.x;                       // b*C + c  (block-uniform)
    const int c  = bc % CC;

    const float* xp = x   + (size_t)bc * (HH * WW);
    float*       op = out + (size_t)bc * (HH * WW);

    // Block-uniform coefficients
    float kk[9];
#pragma unroll
    for (int i = 0; i < 9; ++i) kk[i] = kern[c * 9 + i];
    const float gwc = gw[c];
    const float gbc = gb[c];

    // Zero the 16B left/right pads of all 32 ring rows: 32 rows x 8 floats = 256 = blockDim.
    // Pads are never overwritten; they provide the W-edge zero halo for free.
    {
        const int row = tid >> 3, p = tid & 7;
        smem[row * ROWF + (p < 4 ? p : 128 + p)] = 0.0f;   // 0..3 and 132..135
    }

    // Group q holds padded rows pr = 8q..8q+7, i.e. real rows r = 8q-8 .. 8q-1.
    auto ldgrp = [&](int q) -> vf4 {
        const int r = GR * q - GR + rs;
        if (r >= 0 && r < HH) return *(const vf4*)(xp + r * WW + col);
        return (vf4)(0.0f);
    };
    auto wrgrp = [&](int q, vf4 v) {
        *(vf4*)(&smem[(q & 3) * SLOTF + rs * ROWF + 4 + col]) = v;
    };

    // ---- Prologue: groups 0..2 into LDS; groups 3,4 in flight in regs ----
    {
        vf4 t0 = ldgrp(0), t1 = ldgrp(1), t2 = ldgrp(2);
        wrgrp(0, t0); wrgrp(1, t1); wrgrp(2, t2);
    }
    vf4 buf[3];
    buf[0] = ldgrp(3);
    buf[1] = ldgrp(4);
    buf[2] = (vf4)(0.0f);
    asm volatile("s_waitcnt lgkmcnt(0)" ::: "memory");
    __builtin_amdgcn_s_barrier();

    // ---- Main loop: block sweeps the image 8 contiguous rows per iteration ----
    // iter g: ds_write group g+3 (loaded 2 iters ago), issue load group g+5,
    //         barrier, compute output rows 8g..8g+7 from groups g..g+2, barrier.
#pragma unroll
    for (int g = 0; g < NG; ++g) {
        if (g + 3 <= 17) wrgrp(g + 3, buf[g % 3]);           // reg -> LDS (counted vmcnt wait)
        if (g + 5 <= 17) buf[(g + 2) % 3] = ldgrp(g + 5);    // issue next global load early
        __builtin_amdgcn_sched_barrier(0);
        asm volatile("s_waitcnt lgkmcnt(0)" ::: "memory");   // own ds_write committed
        __builtin_amdgcn_s_barrier();                        // all waves' writes visible
        // NOTE: raw barrier, no vmcnt drain -> global prefetches stay in flight.

        const int ro  = GR * g + rs;      // output row
        const int prm = ro + 7;           // padded rows ro-1, ro, ro+1
        const int pr0 = ro + 8;
        const int prp = ro + 9;
        const float* bm = &smem[((prm >> 3) & 3) * SLOTF + (prm & 7) * ROWF + 4];
        const float* b0 = &smem[((pr0 >> 3) & 3) * SLOTF + (pr0 & 7) * ROWF + 4];
        const float* bp = &smem[((prp >> 3) & 3) * SLOTF + (prp & 7) * ROWF + 4];

        const vf2 Lm = *(const vf2*)(bm + col - 2);   // .y = col-1
        const vf4 Mm = *(const vf4*)(bm + col);       // col..col+3
        const vf2 Rm = *(const vf2*)(bm + col + 4);   // .x = col+4
        const vf2 L0 = *(const vf2*)(b0 + col - 2);
        const vf4 M0 = *(const vf4*)(b0 + col);
        const vf2 R0 = *(const vf2*)(b0 + col + 4);
        const vf2 Lp = *(const vf2*)(bp + col - 2);
        const vf4 Mp = *(const vf4*)(bp + col);
        const vf2 Rp = *(const vf2*)(bp + col + 4);

        const float t0 = __builtin_amdgcn_rcpf(1.0f + __expf(-fmaf(M0.x, gwc, gbc)));
        const float t1 = __builtin_amdgcn_rcpf(1.0f + __expf(-fmaf(M0.y, gwc, gbc)));
        const float t2 = __builtin_amdgcn_rcpf(1.0f + __expf(-fmaf(M0.z, gwc, gbc)));
        const float t3 = __builtin_amdgcn_rcpf(1.0f + __expf(-fmaf(M0.w, gwc, gbc)));

        vf4 o;
        o.x = col9(Lm.y, Mm.x, Mm.y,
                   L0.y, M0.x, M0.y,
                   Lp.y, Mp.x, Mp.y, t0, kk);
        o.y = col9(Mm.x, Mm.y, Mm.z,
                   M0.x, M0.y, M0.z,
                   Mp.x, Mp.y, Mp.z, t1, kk);
        o.z = col9(Mm.y, Mm.z, Mm.w,
                   M0.y, M0.z, M0.w,
                   Mp.y, Mp.z, Mp.w, t2, kk);
        o.w = col9(Mm.z, Mm.w, Rm.x,
                   M0.z, M0.w, R0.x,
                   Mp.z, Mp.w, Rp.x, t3, kk);

        *(vf4*)(op + ro * WW + col) = o;

        __builtin_amdgcn_sched_barrier(0);
        __builtin_amdgcn_s_barrier();    // reads done before next iter overwrites slot
    }
}

extern "C" void kernel_launch(void* const* d_in, const int* in_sizes, int n_in,
                              void* d_out, int out_size, void* d_ws, size_t ws_size,
                              hipStream_t stream) {
    const float* x    = (const float*)d_in[0];
    const float* kern = (const float*)d_in[1];
    const float* gw   = (const float*)d_in[2];
    const float* gb   = (const float*)d_in[3];
    float* out        = (float*)d_out;

    // 1536 blocks = 6/CU (the better R1 residency). Each block is now ONE
    // sequential 64KB read stream + ONE sequential 64KB write stream
    // (8 rows = 4KB contiguous per iteration) instead of 8 thin 512B-step
    // streams -> 8x fewer, 8x fatter DRAM streams.
    dim3 grid(BB * CC);
    dim3 block(256);
    dynmorph_kernel<<<grid, block, 0, stream>>>(x, kern, gw, gb, out);
}

// Round 4
// 181.470 us; speedup vs baseline: 1.0315x; 1.0193x over previous
//
#include <hip/hip_runtime.h>
#include <math.h>

// Problem constants (from reference setup_inputs)
#define BB 8
#define CC 192
#define HH 128
#define WW 128
#define IMGF (HH * WW)      // 16384 floats per (b,c) image
#define NWAVE 6144          // 1536 blocks x 4 waves
#define NSTEP 4             // 24576 chunks / 6144 waves
// chunk = 8 consecutive rows of one image (16 chunks per image).
// Wave w processes chunks s*NWAVE + w, s = 0..3: at any instant the whole
// device's addresses lie in ONE contiguous ~25 MB window sweeping the tensor
// (copy-like macro ordering), instead of 1536 windows spanning all 100 MB.

typedef float vf4 __attribute__((ext_vector_type(4)));

__device__ __forceinline__ float col9(float a0, float a1, float a2,
                                      float b0, float b1, float b2,
                                      float c0, float c1, float c2,
                                      float th, const float* kk) {
    float m;
    m = fmaf(th, kk[0], a0);
    m = fmaxf(m, fmaf(th, kk[1], a1));
    m = fmaxf(m, fmaf(th, kk[2], a2));
    m = fmaxf(m, fmaf(th, kk[3], b0));
    m = fmaxf(m, fmaf(th, kk[4], b1));
    m = fmaxf(m, fmaf(th, kk[5], b2));
    m = fmaxf(m, fmaf(th, kk[6], c0));
    m = fmaxf(m, fmaf(th, kk[7], c1));
    m = fmaxf(m, fmaf(th, kk[8], c2));
    return m;
}

__global__ __launch_bounds__(256) void dynmorph_kernel(
    const float* __restrict__ x,      // [B, C, H, W]
    const float* __restrict__ kern,   // [C, 9]
    const float* __restrict__ gw,     // [C]
    const float* __restrict__ gb,     // [C]
    float* __restrict__ out)          // [B, C, H, W]
{
    const int tid  = threadIdx.x;
    const int lane = tid & 63;
    const int wg   = lane & 31;                 // column group: cols 4*wg..4*wg+3
    const int hf   = lane >> 5;                 // wave half: rows +0..3 / +4..7
    const int col  = wg * 4;
    // Force wave-uniform scalar so c-indexed coefficient reads become s_loads.
    const int wv   = __builtin_amdgcn_readfirstlane((int)(threadIdx.x >> 6));
    const int w    = blockIdx.x * 4 + wv;       // global wave id, 0..6143

#pragma unroll
    for (int s = 0; s < NSTEP; ++s) {
        const int p   = s * NWAVE + w;          // chunk id (wave-uniform)
        const int bc  = p >> 4;                 // image id = b*C + c
        const int c   = bc % CC;
        const int ir0 = ((p & 15) << 3) + (hf << 2);   // local first output row of this half

        const float* xb = x   + (size_t)bc * IMGF;
        float*       ob = out + (size_t)bc * IMGF;

        float kk[9];
#pragma unroll
        for (int i = 0; i < 9; ++i) kk[i] = kern[c * 9 + i];
        const float gwc = gw[c];
        const float gbc = gb[c];

        // Load the 6 input rows this half needs (ir0-1 .. ir0+4), zero at image edges.
        vf4 buf[6];
#pragma unroll
        for (int j = 0; j < 6; ++j) {
            const int lr = ir0 - 1 + j;
            buf[j] = (lr >= 0 && lr < HH) ? *(const vf4*)(xb + lr * WW + col)
                                          : (vf4)(0.0f);
        }

        // Column halos per row (shfl crosses the half boundary only at wg==0/31,
        // where the result is masked to the zero W-edge halo anyway).
        float lf[6], rt[6];
#pragma unroll
        for (int j = 0; j < 6; ++j) {
            const float l = __shfl_up(buf[j].w, 1);
            const float r = __shfl_down(buf[j].x, 1);
            lf[j] = (wg == 0)  ? 0.0f : l;
            rt[j] = (wg == 31) ? 0.0f : r;
        }

        // Compute the 4 output rows ir0..ir0+3.
#pragma unroll
        for (int j = 0; j < 4; ++j) {
            const vf4 A  = buf[j];
            const vf4 B  = buf[j + 1];
            const vf4 Cv = buf[j + 2];

            const float t0 = __builtin_amdgcn_rcpf(1.0f + __expf(-fmaf(B.x, gwc, gbc)));
            const float t1 = __builtin_amdgcn_rcpf(1.0f + __expf(-fmaf(B.y, gwc, gbc)));
            const float t2 = __builtin_amdgcn_rcpf(1.0f + __expf(-fmaf(B.z, gwc, gbc)));
            const float t3 = __builtin_amdgcn_rcpf(1.0f + __expf(-fmaf(B.w, gwc, gbc)));

            vf4 o;
            o.x = col9(lf[j],     A.x, A.y,
                       lf[j + 1], B.x, B.y,
                       lf[j + 2], Cv.x, Cv.y, t0, kk);
            o.y = col9(A.x, A.y, A.z,
                       B.x, B.y, B.z,
                       Cv.x, Cv.y, Cv.z, t1, kk);
            o.z = col9(A.y, A.z, A.w,
                       B.y, B.z, B.w,
                       Cv.y, Cv.z, Cv.w, t2, kk);
            o.w = col9(A.z, A.w, rt[j],
                       B.z, B.w, rt[j + 1],
                       Cv.z, Cv.w, rt[j + 2], t3, kk);

            *(vf4*)(ob + (ir0 + j) * WW + col) = o;
        }
    }
}

extern "C" void kernel_launch(void* const* d_in, const int* in_sizes, int n_in,
                              void* d_out, int out_size, void* d_ws, size_t ws_size,
                              hipStream_t stream) {
    const float* x    = (const float*)d_in[0];
    const float* kern = (const float*)d_in[1];
    const float* gw   = (const float*)d_in[2];
    const float* gb   = (const float*)d_in[3];
    float* out        = (float*)d_out;

    dim3 grid(BB * CC);   // 1536 blocks = 6/CU; mapping (not grid) changed this round
    dim3 block(256);
    dynmorph_kernel<<<grid, block, 0, stream>>>(x, kern, gw, gb, out);
}